// Round 20
// baseline (341.694 us; speedup 1.0000x reference)
//
#include <hip/hip_runtime.h>

typedef short short8 __attribute__((ext_vector_type(8)));
typedef float f32x4 __attribute__((ext_vector_type(4)));
typedef float f32x2 __attribute__((ext_vector_type(2)));
typedef unsigned int uint;

#define C_IN  128
#define H_IN  112
#define W_IN  112
#define K_OUT 256
#define H_OUTD 110
#define W_OUTD 110
#define NBATCH 32

// F2 layout: [S(36)][wm(4)][mt(4)][lane(64)][e(8)], S = ph*18 + rs*2 + ch2
//   k = wm*64+mt*16+(lane&15) ; c = ph*64 + ch2*32 + (lane>>4)*8 + e
#define F_ELEMS  (36*4*4*64*8)             // 294,912

__device__ __forceinline__ unsigned short f2bf(float f) {
  uint u = __float_as_uint(f);
  u += 0x7fffu + ((u >> 16) & 1u);   // RNE
  return (unsigned short)(u >> 16);
}

// hardware packed f32x2 -> bf16x2 (RNE), single VALU instr
__device__ __forceinline__ uint cvt_pk_bf16(float lo, float hi) {
  uint v;
  asm("v_cvt_pk_bf16_f32 %0, %1, %2" : "=v"(v) : "v"(lo), "v"(hi));
  return v;
}

// ---- prep: filt (OIHW f32) -> F2 fragment-packed bf16 (ph-major slices) ----
__global__ __launch_bounds__(256) void fprep_kernel(const float* __restrict__ ft,
                                                    unsigned short* __restrict__ F) {
  int idx = blockIdx.x*256 + threadIdx.x;   // < 294912
  int e    = idx & 7;
  int lane = (idx >> 3) & 63;
  int mt   = (idx >> 9) & 3;
  int wm   = (idx >> 11) & 3;
  int S    = idx >> 13;                     // 0..35
  int ph   = S >= 18;
  int j    = S - ph*18;
  int rs   = j >> 1;
  int ch2  = j & 1;
  int k = wm*64 + mt*16 + (lane & 15);
  int c = ph*64 + ch2*32 + (lane >> 4)*8 + e;
  F[idx] = f2bf(ft[(k*C_IN + c)*9 + rs]);
}

// ---------------- persistent fused implicit-GEMM conv ----------------
// 512 persistent blocks (2/CU), each owns ~12 tiles (XCD-chunked, slot-strided).
// Double-buffered halo: K-loop on buf[cur] while staging next tile's halo into
// buf[cur^1], split issue(step4/20)->consume(step8/24) so latency hides under
// MFMAs. One __syncthreads per tile. K-loop body = R16 (reg-dbuf both streams,
// conflict-free 16x16 maps, no barriers).
__global__ __launch_bounds__(256, 2) void conv_gemm(const float* __restrict__ x,
                                                    const unsigned short* __restrict__ F,
                                                    float* __restrict__ out) {
  __shared__ unsigned short smX[2][2*108*64];   // 2 x 27,648 B
  const int b    = blockIdx.x;                  // 0..511
  const int xcd  = b & 7;
  const int slot = b >> 3;                      // 0..63
  const int tid  = threadIdx.x;
  const int lane = tid & 63;
  const int wm   = tid >> 6;                    // M quadrant (64 k each)
  const int l15  = lane & 15;
  const int lhi  = lane >> 4;

  int browb[4];
  #pragma unroll
  for (int nt = 0; nt < 4; ++nt)
    browb[nt] = (nt*18 + l15)*64;

  const unsigned short* Aw = F + wm*2048 + lane*8;

  // tile params: g = xcd*784 + t ; n = g/196 ; tile196 = g%196
  auto TP = [&](int t, int& nn, int& h0, int& w0) {
    int g = xcd*784 + t;
    nn = g / 196;
    int t196 = g - nn*196;
    int th = t196 / 7;
    h0 = th*4;
    w0 = (t196 - th*7)*16;
  };

  // staging temps (held across K-steps during issue->consume window)
  f32x4 s0[4], s1[4];
  f32x2 st0, st1;
  int   sc0;                                    // row's channel base

  // PH_A: issue the 10 vector loads for row r of tile (nn,h0,w0)
  auto PH_A = [&](int r, int nn, int h0, int w0) {
    int hh = r >> 6;
    int cp = r & 63;
    sc0 = cp*2;
    int hc = h0 + hh; if (hc > 111) hc = 111;
    const float* p0 = x + (((size_t)nn*C_IN + sc0)*H_IN + hc)*W_IN + w0;
    const float* p1 = p0 + H_IN*W_IN;
    #pragma unroll
    for (int q = 0; q < 4; ++q) {
      s0[q] = *(const f32x4*)(p0 + q*4);
      s1[q] = *(const f32x4*)(p1 + q*4);
    }
    const int toff = (w0 == 96) ? 12 : 16;      // tail clamp (feeds only discarded cols)
    st0 = *(const f32x2*)(p0 + toff);
    st1 = *(const f32x2*)(p1 + toff);
  };
  // PH_B: cvt + swizzled ds_write of the held row into dst buffer
  auto PH_B = [&](int r, unsigned short* dst) {
    int hh = r >> 6;
    const int cin = sc0 & 63;
    unsigned short* d = dst + (sc0 >> 6)*6912 + hh*1152;
    #pragma unroll
    for (int j = 0; j < 18; ++j) {
      float f0 = (j < 16) ? s0[j >> 2][j & 3] : st0[j - 16];
      float f1 = (j < 16) ? s1[j >> 2][j & 3] : st1[j - 16];
      uint inner = (uint)cin ^ (((uint)j & 7u) << 3);
      *(uint*)&d[j*64 + inner] = cvt_pk_bf16(f0, f1);
    }
  };

  auto BOFF = [&](int S) {
    const int ph  = (S >= 18);
    const int jj  = S - ph*18;
    const int rs  = jj >> 1, ch2 = jj & 1;
    const int r   = rs/3, s = rs - r*3;
    const int key = ((l15 + s) & 7) << 3;
    return ph*6912 + (r*18 + s)*64 + ((ch2*32 + lhi*8) ^ key);
  };

#define MFMAS(A, B)                                                              \
  {                                                                              \
    __builtin_amdgcn_s_setprio(1);                                               \
    _Pragma("unroll")                                                            \
    for (int nt = 0; nt < 4; ++nt) {                                             \
      _Pragma("unroll")                                                          \
      for (int mt = 0; mt < 4; ++mt)                                             \
        acc[mt][nt] = __builtin_amdgcn_mfma_f32_16x16x32_bf16(A[mt], B[nt], acc[mt][nt], 0, 0, 0); \
    }                                                                            \
    __builtin_amdgcn_s_setprio(0);                                               \
  }

  // ---- prologue: stage first tile into buf 0 ----
  int cn, ch0, cw0;
  TP(slot, cn, ch0, cw0);
  PH_A(tid, cn, ch0, cw0);
  PH_B(tid, smX[0]);
  if (tid < 128) {
    PH_A(256 + tid, cn, ch0, cw0);
    PH_B(256 + tid, smX[0]);
  }
  __syncthreads();

  int cur = 0;
  for (int t = slot; t < 784; t += 64, cur ^= 1) {
    const bool hasNext = (t + 64) < 784;
    int nn2 = 0, nh0 = 0, nw0 = 0;
    if (hasNext) TP(t + 64, nn2, nh0, nw0);
    unsigned short* dstN = smX[cur ^ 1];
    const unsigned short* src = smX[cur];

    f32x4 acc[4][4];
    #pragma unroll
    for (int mt = 0; mt < 4; ++mt)
      #pragma unroll
      for (int nt = 0; nt < 4; ++nt)
        acc[mt][nt] = (f32x4){0.f, 0.f, 0.f, 0.f};

    short8 aP[4], aQ[4], bP[4], bQ[4];
    #pragma unroll
    for (int u = 0; u < 4; ++u)
      aP[u] = *(const short8*)(Aw + u*512);
    {
      const int boff = BOFF(0);
      #pragma unroll
      for (int nt = 0; nt < 4; ++nt)
        bP[nt] = *(const short8*)&src[browb[nt] + boff];
    }

    for (int i = 0; i < 36; i += 2) {
      {
        const unsigned short* As = Aw + (size_t)(i + 1)*8192;
        #pragma unroll
        for (int u = 0; u < 4; ++u)
          aQ[u] = *(const short8*)(As + u*512);
        const int boff = BOFF(i + 1);
        #pragma unroll
        for (int nt = 0; nt < 4; ++nt)
          bQ[nt] = *(const short8*)&src[browb[nt] + boff];
      }
      MFMAS(aP, bP);
      // staged prefetch of next tile's halo (issue -> consume 4 steps later)
      if (hasNext) {
        if (i == 4)  PH_A(tid, nn2, nh0, nw0);
        else if (i == 8)  PH_B(tid, dstN);
        else if (i == 20) { if (tid < 128) PH_A(256 + tid, nn2, nh0, nw0); }
        else if (i == 24) { if (tid < 128) PH_B(256 + tid, dstN); }
      }
      if (i + 2 < 36) {
        const unsigned short* As = Aw + (size_t)(i + 2)*8192;
        #pragma unroll
        for (int u = 0; u < 4; ++u)
          aP[u] = *(const short8*)(As + u*512);
        const int boff = BOFF(i + 2);
        #pragma unroll
        for (int nt = 0; nt < 4; ++nt)
          bP[nt] = *(const short8*)&src[browb[nt] + boff];
      }
      MFMAS(aQ, bQ);
    }

    // epilogue: D frag: col(px)=l15, row(k)=lhi*4+reg
    {
      const int wv = cw0 + l15;
      #pragma unroll
      for (int nt = 0; nt < 4; ++nt) {
        int hv = ch0 + nt;
        if (hv < H_OUTD && wv < W_OUTD) {
          float* po = out + (size_t)cn*K_OUT*(H_OUTD*W_OUTD) + hv*W_OUTD + wv;
          #pragma unroll
          for (int mt = 0; mt < 4; ++mt) {
            #pragma unroll
            for (int reg = 0; reg < 4; ++reg) {
              int k = wm*64 + mt*16 + lhi*4 + reg;
              po[(size_t)k*(H_OUTD*W_OUTD)] = acc[mt][nt][reg];
            }
          }
        }
      }
    }

    __syncthreads();   // next buf staged; all reads of cur done (safe to overwrite)
    cn = nn2; ch0 = nh0; cw0 = nw0;
  }
#undef MFMAS
}

// ---------------- fallback (ws too small): naive fp32 ----------------
__global__ void naive_conv(const float* __restrict__ x, const float* __restrict__ ft,
                           float* __restrict__ out) {
  int idx = blockIdx.x*256 + threadIdx.x;
  int total = NBATCH*K_OUT*H_OUTD*W_OUTD;
  if (idx >= total) return;
  int w = idx % W_OUTD; int t = idx / W_OUTD;
  int h = t % H_OUTD; t /= H_OUTD;
  int k = t % K_OUT; int nn = t / K_OUT;
  float acc = 0.f;
  for (int c = 0; c < C_IN; ++c)
    for (int r = 0; r < 3; ++r)
      for (int s = 0; s < 3; ++s)
        acc += x[((size_t)(nn*C_IN + c)*H_IN + h + r)*W_IN + w + s]
             * ft[((k*C_IN + c)*3 + r)*3 + s];
  out[idx] = acc;
}

extern "C" void kernel_launch(void* const* d_in, const int* in_sizes, int n_in,
                              void* d_out, int out_size, void* d_ws, size_t ws_size,
                              hipStream_t stream) {
  (void)in_sizes; (void)n_in; (void)out_size;
  const float* x  = (const float*)d_in[0];
  const float* ft = (const float*)d_in[1];
  float* out = (float*)d_out;
  size_t need = (size_t)F_ELEMS * sizeof(unsigned short);
  if (ws_size >= need) {
    unsigned short* F = (unsigned short*)d_ws;
    fprep_kernel<<<dim3(1152), 256, 0, stream>>>(ft, F);
    conv_gemm<<<dim3(512), 256, 0, stream>>>(x, F, out);
  } else {
    int total = NBATCH*K_OUT*H_OUTD*W_OUTD;
    naive_conv<<<(total + 255)/256, 256, 0, stream>>>(x, ft, out);
  }
}